// Round 5
// baseline (378.910 us; speedup 1.0000x reference)
//
#include <hip/hip_runtime.h>

#define NB 512
#define NPG 256
#define NTOT (NB * NPG)
#define RS 68   // hsh row stride in floats (64 + 4 pad): chunk bank-group = (row+chunk)&7
#define NEGMIN -3.4028234663852886e38f

// workspace layout (float offsets)
#define OFF_WNT 0       // WnT[64][16]   WnT[d][k] = Wn[k][d]
#define OFF_WCT 1024    // WcT[64][64]   WcT[d][k] = Wc[k][d]
#define OFF_W1AT 5120   // W1aT[128][64] W1aT[j][k] = W1[k][j]      (rows 0..63 of W1)
#define OFF_W1BT 13312  // W1bT[128][64] W1bT[j][k] = W1[64+k][j]   (rows 64..127)
#define OFF_BNC 21504   // bn + bc [64]
#define WS_FLOATS 21568

__global__ __launch_bounds__(256) void prep_kernel(
    const float* __restrict__ Wn, const float* __restrict__ bn,
    const float* __restrict__ Wc, const float* __restrict__ bc,
    const float* __restrict__ W1, float* __restrict__ ws)
{
    int i = blockIdx.x * 256 + threadIdx.x;
    if (i < 1024) {
        int d = i >> 4, k = i & 15;
        ws[OFF_WNT + i] = Wn[k * 64 + d];
    } else if (i < 5120) {
        int j = i - 1024; int d = j >> 6, k = j & 63;
        ws[OFF_WCT + j] = Wc[k * 64 + d];
    } else if (i < 13312) {
        int j = i - 5120; int r = j >> 6, k = j & 63;
        ws[OFF_W1AT + j] = W1[k * 128 + r];
    } else if (i < 21504) {
        int j = i - 13312; int r = j >> 6, k = j & 63;
        ws[OFF_W1BT + j] = W1[(64 + k) * 128 + r];
    } else if (i < WS_FLOATS) {
        int d = i - OFF_BNC;
        ws[OFF_BNC + d] = bn[d] + bc[d];
    }
}

// One block (512 threads) per graph. node = tid&255, dim-half u = tid>>8.
// waves_per_eu(4,4): dynamic LDS hides the 2-block/CU cap from the backend;
// without the max=4 pin the allocator chases 8 waves/EU and squeezes to
// 64 VGPRs, rematerializing pf[64] via LDS re-reads (R4: 304us vs 183).
// NUMERICS: all accumulation chains bitwise-identical to validated R2.
__global__ __launch_bounds__(512)
__attribute__((amdgpu_waves_per_eu(4, 4)))
void gdqn_kernel(
    const float* __restrict__ nfg, const int* __restrict__ esrcg,
    const int* __restrict__ fmask, const float* __restrict__ ws,
    const float* __restrict__ bn, const float* __restrict__ b1,
    const float* __restrict__ W2, const float* __restrict__ b2,
    float* __restrict__ out)
{
    extern __shared__ float smem[];
    float* hsh  = smem;                     // 256*68 = 17408
    float* part = smem + 17408;             // 512
    float* gesh = smem + 17920;             // 64
    float* rpsh = smem + 17984;             // 128
    float* redv = smem + 18112;             // 4
    int*   redi = (int*)(smem + 18116);     // 4  -> total 18120 floats

    const int g = blockIdx.x, tid = threadIdx.x;
    const int n = tid & 255;                // node (lane-varying)
    const int u = tid >> 8;                 // dim half (wave-uniform)
    const int d0 = u << 5;                  // first dim of my half
    const int node = (g << 8) + n;

    const float* WnT  = ws + OFF_WNT;
    const float* WcT  = ws + OFF_WCT;
    const float* W1aT = ws + OFF_W1AT;
    const float* bnc  = ws + OFF_BNC;

    float* myrow  = hsh + n * RS;           // full 64-float row of my node
    float* myhalf = myrow + d0;             // my 32-float half (8 chunks)

    // node features -> regs (statically indexed everywhere)
    float nf[16];
    {
        const float4* p = (const float4*)(nfg + node * 16);
        float4 a = p[0], b = p[1], c = p[2], d = p[3];
        nf[0]=a.x; nf[1]=a.y; nf[2]=a.z; nf[3]=a.w;
        nf[4]=b.x; nf[5]=b.y; nf[6]=b.z; nf[7]=b.w;
        nf[8]=c.x; nf[9]=c.y; nf[10]=c.z; nf[11]=c.w;
        nf[12]=d.x; nf[13]=d.y; nf[14]=d.z; nf[15]=d.w;
    }
    int es[16];
    {
        const int4* p = (const int4*)(esrcg + node * 16);
        int4 a = p[0], b = p[1], c = p[2], d = p[3];
        es[0]=a.x&255; es[1]=a.y&255; es[2]=a.z&255; es[3]=a.w&255;
        es[4]=b.x&255; es[5]=b.y&255; es[6]=b.z&255; es[7]=b.w&255;
        es[8]=c.x&255; es[9]=c.y&255; es[10]=c.z&255; es[11]=c.w&255;
        es[12]=d.x&255; es[13]=d.y&255; es[14]=d.z&255; es[15]=d.w&255;
    }

    // h0 = relu(nf @ Wn + bn) for my 32 dims -> LDS
    for (int cc = 0; cc < 8; ++cc) {        // cc wave-uniform
        float s4[4];
        #pragma unroll
        for (int q = 0; q < 4; ++q) {
            int d = d0 + 4 * cc + q;
            float s = bn[d];
            #pragma unroll
            for (int k = 0; k < 16; ++k) s = fmaf(nf[k], WnT[d * 16 + k], s);
            s4[q] = fmaxf(s, 0.0f);
        }
        ((float4*)myhalf)[cc] = make_float4(s4[0], s4[1], s4[2], s4[3]);
    }
    __syncthreads();

    for (int lv = 0; lv < 3; ++lv) {
        // gather my 32 dims over 16 neighbors (imm-offset b128 reads)
        float pooled[32];
        #pragma unroll
        for (int k = 0; k < 32; ++k) pooled[k] = 0.0f;
        #pragma unroll
        for (int j = 0; j < 16; ++j) {
            const float4* row = (const float4*)(hsh + es[j] * RS + d0);
            #pragma unroll
            for (int cc = 0; cc < 8; ++cc) {
                float4 v = row[cc];
                pooled[4*cc+0] += v.x; pooled[4*cc+1] += v.y;
                pooled[4*cc+2] += v.z; pooled[4*cc+3] += v.w;
            }
        }
        __syncthreads();                    // old h fully consumed

        // exchange: write my pooled half into my row, read back full row
        #pragma unroll
        for (int cc = 0; cc < 8; ++cc)
            ((float4*)myhalf)[cc] = make_float4(pooled[4*cc], pooled[4*cc+1],
                                                pooled[4*cc+2], pooled[4*cc+3]);
        __syncthreads();                    // both halves visible
        float pf[64];
        #pragma unroll
        for (int c = 0; c < 16; ++c) {
            float4 v = ((const float4*)myrow)[c];
            pf[4*c+0] = v.x; pf[4*c+1] = v.y; pf[4*c+2] = v.z; pf[4*c+3] = v.w;
        }
        __syncthreads();                    // reads done before h overwrite

        // h = relu(pooled @ Wc + (bn+bc) + nf@Wn) for my 32 dims -> LDS
        for (int cc = 0; cc < 8; ++cc) {
            float s4[4];
            #pragma unroll
            for (int q = 0; q < 4; ++q) {
                int d = d0 + 4 * cc + q;
                float s = bnc[d];
                #pragma unroll
                for (int k = 0; k < 16; ++k) s = fmaf(nf[k], WnT[d * 16 + k], s);
                const float* wr = WcT + d * 64;
                #pragma unroll
                for (int k = 0; k < 64; ++k) s = fmaf(pf[k], wr[k], s);
                s4[q] = fmaxf(s, 0.0f);
            }
            ((float4*)myhalf)[cc] = make_float4(s4[0], s4[1], s4[2], s4[3]);
        }
        __syncthreads();
    }

    // graph_embed = relu(sum over nodes of h)  (same association as R2)
    if (tid < 256) {
        int col = tid & 63, v0 = (tid >> 6) << 6;
        float s = 0.0f;
        for (int v = 0; v < 64; ++v) s += hsh[(v0 + v) * RS + col];
        part[tid] = s;
    }
    __syncthreads();
    if (tid < 64) {
        float s = part[tid] + part[tid + 64] + part[tid + 128] + part[tid + 192];
        gesh[tid] = fmaxf(s, 0.0f);
    }
    __syncthreads();
    // rep_proj[j] = b1[j] + sum_k ge[k] * W1[64+k][j]
    if (tid < 128) {
        float s = b1[tid];
        const float4* wr = (const float4*)(ws + OFF_W1BT + tid * 64);
        #pragma unroll
        for (int c = 0; c < 16; ++c) {
            float4 w = wr[c];
            s = fmaf(gesh[4*c+0], w.x, s);
            s = fmaf(gesh[4*c+1], w.y, s);
            s = fmaf(gesh[4*c+2], w.z, s);
            s = fmaf(gesh[4*c+3], w.w, s);
        }
        rpsh[tid] = s;
    }

    // reload full h for my node (only tid<256 uses it)
    float h[64];
    #pragma unroll
    for (int c = 0; c < 16; ++c) {
        float4 v = ((const float4*)myrow)[c];
        h[4*c+0] = v.x; h[4*c+1] = v.y; h[4*c+2] = v.z; h[4*c+3] = v.w;
    }
    __syncthreads();                        // rpsh visible

    // raw = relu([h,rep]@W1+b1) @ W2 + b2 — FULL sequential j-chain on
    // tid<256 (bitwise identical to R2; split chains flip the argmax — R3)
    float raw = 0.0f;
    if (tid < 256) {
        raw = b2[0];
        for (int j = 0; j < 128; ++j) {     // wave-uniform j; h[k] static
            float z = rpsh[j];
            const float* wr = W1aT + j * 64;
            #pragma unroll
            for (int k = 0; k < 64; ++k) z = fmaf(h[k], wr[k], z);
            raw = fmaf(fmaxf(z, 0.0f), W2[j], raw);
        }
        out[512 + node] = raw;
    }

    // masked max/argmax over the graph (first-index tie-break)
    float q = NEGMIN;
    if (tid < 256) q = fmask[node] ? NEGMIN : raw;
    int idx = n;
    #pragma unroll
    for (int off = 32; off >= 1; off >>= 1) {
        float ov = __shfl_down(q, off, 64);
        int oi  = __shfl_down(idx, off, 64);
        if (ov > q || (ov == q && oi < idx)) { q = ov; idx = oi; }
    }
    if (tid < 256 && (tid & 63) == 0) { redv[tid >> 6] = q; redi[tid >> 6] = idx; }
    __syncthreads();
    if (tid == 0) {
        float bv = redv[0]; int bi = redi[0];
        #pragma unroll
        for (int w = 1; w < 4; ++w) {
            float v = redv[w]; int iw = redi[w];
            if (v > bv || (v == bv && iw < bi)) { bv = v; bi = iw; }
        }
        out[g] = (float)bi;                 // indices (as float)
        out[512 + NTOT + g] = bv;           // values
    }
}

extern "C" void kernel_launch(void* const* d_in, const int* in_sizes, int n_in,
                              void* d_out, int out_size, void* d_ws, size_t ws_size,
                              hipStream_t stream)
{
    const float* nfg   = (const float*)d_in[0];
    const int*   esrc  = (const int*)d_in[1];
    const int*   fmask = (const int*)d_in[4];
    const float* Wn = (const float*)d_in[5];
    const float* bn = (const float*)d_in[6];
    const float* Wc = (const float*)d_in[7];
    const float* bc = (const float*)d_in[8];
    const float* W1 = (const float*)d_in[9];
    const float* b1 = (const float*)d_in[10];
    const float* W2 = (const float*)d_in[11];
    const float* b2 = (const float*)d_in[12];
    float* out = (float*)d_out;
    float* ws  = (float*)d_ws;

    prep_kernel<<<(WS_FLOATS + 255) / 256, 256, 0, stream>>>(Wn, bn, Wc, bc, W1, ws);

    size_t shmem = 18120 * sizeof(float);   // 72,480 B -> 2 blocks/CU (145 KB/160 KB)
    hipFuncSetAttribute((const void*)gdqn_kernel,
                        hipFuncAttributeMaxDynamicSharedMemorySize, (int)shmem);
    gdqn_kernel<<<NB, 512, shmem, stream>>>(nfg, esrc, fmask, ws, bn, b1, W2, b2, out);
}

// Round 6
// 371.268 us; speedup vs baseline: 1.0206x; 1.0206x over previous
//
#include <hip/hip_runtime.h>

#define NB 512
#define NPG 256
#define NTOT (NB * NPG)
#define RS 68   // hsh row stride in floats (64 + 4 pad): chunk bank-group = (row+chunk)&7
#define NEGMIN -3.4028234663852886e38f

// workspace layout (float offsets)
#define OFF_WNT 0       // WnT[64][16]   WnT[d][k] = Wn[k][d]
#define OFF_WCT 1024    // WcT[64][64]   WcT[d][k] = Wc[k][d]
#define OFF_W1AT 5120   // W1aT[128][64] W1aT[j][k] = W1[k][j]      (rows 0..63 of W1)
#define OFF_W1BT 13312  // W1bT[128][64] W1bT[j][k] = W1[64+k][j]   (rows 64..127)
#define OFF_BNC 21504   // bn + bc [64]
#define WS_FLOATS 21568

__global__ __launch_bounds__(256) void prep_kernel(
    const float* __restrict__ Wn, const float* __restrict__ bn,
    const float* __restrict__ Wc, const float* __restrict__ bc,
    const float* __restrict__ W1, float* __restrict__ ws)
{
    int i = blockIdx.x * 256 + threadIdx.x;
    if (i < 1024) {
        int d = i >> 4, k = i & 15;
        ws[OFF_WNT + i] = Wn[k * 64 + d];
    } else if (i < 5120) {
        int j = i - 1024; int d = j >> 6, k = j & 63;
        ws[OFF_WCT + j] = Wc[k * 64 + d];
    } else if (i < 13312) {
        int j = i - 5120; int r = j >> 6, k = j & 63;
        ws[OFF_W1AT + j] = W1[k * 128 + r];
    } else if (i < 21504) {
        int j = i - 13312; int r = j >> 6, k = j & 63;
        ws[OFF_W1BT + j] = W1[(64 + k) * 128 + r];
    } else if (i < WS_FLOATS) {
        int d = i - OFF_BNC;
        ws[OFF_BNC + d] = bn[d] + bc[d];
    }
}

// One block (512 threads) per graph. node = tid&255, dim-half u = tid>>8.
// REGISTER ALLOCATOR NOTE (R4/R5 evidence): with min-waves>=4 declared the
// allocator squeezes to the 64-VGPR tier and remats/spills pf[64] (304-312us).
// With min=2 (as in R2's 256-thr shape) it allocates to natural pressure.
// Natural pressure here ~104 regs (pf64+nf16+packed-es4+temps) -> expect
// 96-128 VGPRs -> 2 blocks/CU -> 16 waves/CU = 4 waves/EU.
// NUMERICS: all accumulation chains bitwise-identical to validated R2/R4.
__global__ __launch_bounds__(512, 2) void gdqn_kernel(
    const float* __restrict__ nfg, const int* __restrict__ esrcg,
    const int* __restrict__ fmask, const float* __restrict__ ws,
    const float* __restrict__ bn, const float* __restrict__ b1,
    const float* __restrict__ W2, const float* __restrict__ b2,
    float* __restrict__ out)
{
    extern __shared__ float smem[];
    float* hsh  = smem;                     // 256*68 = 17408
    float* part = smem + 17408;             // 512
    float* gesh = smem + 17920;             // 64
    float* rpsh = smem + 17984;             // 128
    float* redv = smem + 18112;             // 4
    int*   redi = (int*)(smem + 18116);     // 4  -> total 18120 floats

    const int g = blockIdx.x, tid = threadIdx.x;
    const int n = tid & 255;                // node (lane-varying)
    const int u = tid >> 8;                 // dim half (wave-uniform)
    const int d0 = u << 5;                  // first dim of my half
    const int node = (g << 8) + n;

    const float* WnT  = ws + OFF_WNT;
    const float* WcT  = ws + OFF_WCT;
    const float* W1aT = ws + OFF_W1AT;
    const float* bnc  = ws + OFF_BNC;

    float* myrow  = hsh + n * RS;           // full 64-float row of my node
    float* myhalf = myrow + d0;             // my 32-float half (8 chunks)

    // node features -> regs (statically indexed everywhere)
    float nf[16];
    {
        const float4* p = (const float4*)(nfg + node * 16);
        float4 a = p[0], b = p[1], c = p[2], d = p[3];
        nf[0]=a.x; nf[1]=a.y; nf[2]=a.z; nf[3]=a.w;
        nf[4]=b.x; nf[5]=b.y; nf[6]=b.z; nf[7]=b.w;
        nf[8]=c.x; nf[9]=c.y; nf[10]=c.z; nf[11]=c.w;
        nf[12]=d.x; nf[13]=d.y; nf[14]=d.z; nf[15]=d.w;
    }
    // 16 in-edge local indices packed 8-bit into 4 u32s (-12 VGPRs vs int[16])
    unsigned int eb[4];
    {
        const int4* p = (const int4*)(esrcg + node * 16);
        #pragma unroll
        for (int w = 0; w < 4; ++w) {
            int4 a = p[w];
            eb[w] = (unsigned int)(a.x & 255) | ((unsigned int)(a.y & 255) << 8) |
                    ((unsigned int)(a.z & 255) << 16) | ((unsigned int)(a.w & 255) << 24);
        }
    }

    // h0 = relu(nf @ Wn + bn) for my 32 dims -> LDS
    for (int cc = 0; cc < 8; ++cc) {        // cc wave-uniform
        float s4[4];
        #pragma unroll
        for (int q = 0; q < 4; ++q) {
            int d = d0 + 4 * cc + q;
            float s = bn[d];
            #pragma unroll
            for (int k = 0; k < 16; ++k) s = fmaf(nf[k], WnT[d * 16 + k], s);
            s4[q] = fmaxf(s, 0.0f);
        }
        ((float4*)myhalf)[cc] = make_float4(s4[0], s4[1], s4[2], s4[3]);
    }
    __syncthreads();

    for (int lv = 0; lv < 3; ++lv) {
        // gather my 32 dims over 16 neighbors (imm-offset b128 reads)
        float pooled[32];
        #pragma unroll
        for (int k = 0; k < 32; ++k) pooled[k] = 0.0f;
        #pragma unroll
        for (int j = 0; j < 16; ++j) {      // j static -> byte-extract static
            int s = (int)((eb[j >> 2] >> ((j & 3) * 8)) & 255u);
            const float4* row = (const float4*)(hsh + s * RS + d0);
            #pragma unroll
            for (int cc = 0; cc < 8; ++cc) {
                float4 v = row[cc];
                pooled[4*cc+0] += v.x; pooled[4*cc+1] += v.y;
                pooled[4*cc+2] += v.z; pooled[4*cc+3] += v.w;
            }
        }
        __syncthreads();                    // old h fully consumed

        // exchange: write my pooled half into my row, read back full row
        #pragma unroll
        for (int cc = 0; cc < 8; ++cc)
            ((float4*)myhalf)[cc] = make_float4(pooled[4*cc], pooled[4*cc+1],
                                                pooled[4*cc+2], pooled[4*cc+3]);
        __syncthreads();                    // both halves visible
        float pf[64];
        #pragma unroll
        for (int c = 0; c < 16; ++c) {
            float4 v = ((const float4*)myrow)[c];
            pf[4*c+0] = v.x; pf[4*c+1] = v.y; pf[4*c+2] = v.z; pf[4*c+3] = v.w;
        }
        __syncthreads();                    // reads done before h overwrite

        // h = relu(pooled @ Wc + (bn+bc) + nf@Wn) for my 32 dims -> LDS
        for (int cc = 0; cc < 8; ++cc) {
            float s4[4];
            #pragma unroll
            for (int q = 0; q < 4; ++q) {
                int d = d0 + 4 * cc + q;
                float s = bnc[d];
                #pragma unroll
                for (int k = 0; k < 16; ++k) s = fmaf(nf[k], WnT[d * 16 + k], s);
                const float* wr = WcT + d * 64;
                #pragma unroll
                for (int k = 0; k < 64; ++k) s = fmaf(pf[k], wr[k], s);
                s4[q] = fmaxf(s, 0.0f);
            }
            ((float4*)myhalf)[cc] = make_float4(s4[0], s4[1], s4[2], s4[3]);
        }
        __syncthreads();
    }

    // graph_embed = relu(sum over nodes of h)  (same association as R2)
    if (tid < 256) {
        int col = tid & 63, v0 = (tid >> 6) << 6;
        float s = 0.0f;
        for (int v = 0; v < 64; ++v) s += hsh[(v0 + v) * RS + col];
        part[tid] = s;
    }
    __syncthreads();
    if (tid < 64) {
        float s = part[tid] + part[tid + 64] + part[tid + 128] + part[tid + 192];
        gesh[tid] = fmaxf(s, 0.0f);
    }
    __syncthreads();
    // rep_proj[j] = b1[j] + sum_k ge[k] * W1[64+k][j]
    if (tid < 128) {
        float s = b1[tid];
        const float4* wr = (const float4*)(ws + OFF_W1BT + tid * 64);
        #pragma unroll
        for (int c = 0; c < 16; ++c) {
            float4 w = wr[c];
            s = fmaf(gesh[4*c+0], w.x, s);
            s = fmaf(gesh[4*c+1], w.y, s);
            s = fmaf(gesh[4*c+2], w.z, s);
            s = fmaf(gesh[4*c+3], w.w, s);
        }
        rpsh[tid] = s;
    }

    // reload full h for my node (only tid<256 uses it)
    float h[64];
    #pragma unroll
    for (int c = 0; c < 16; ++c) {
        float4 v = ((const float4*)myrow)[c];
        h[4*c+0] = v.x; h[4*c+1] = v.y; h[4*c+2] = v.z; h[4*c+3] = v.w;
    }
    __syncthreads();                        // rpsh visible

    // raw = relu([h,rep]@W1+b1) @ W2 + b2 — FULL sequential j-chain on
    // tid<256 (bitwise identical to R2; split chains flip the argmax — R3)
    float raw = 0.0f;
    if (tid < 256) {
        raw = b2[0];
        for (int j = 0; j < 128; ++j) {     // wave-uniform j; h[k] static
            float z = rpsh[j];
            const float* wr = W1aT + j * 64;
            #pragma unroll
            for (int k = 0; k < 64; ++k) z = fmaf(h[k], wr[k], z);
            raw = fmaf(fmaxf(z, 0.0f), W2[j], raw);
        }
        out[512 + node] = raw;
    }

    // masked max/argmax over the graph (first-index tie-break)
    float q = NEGMIN;
    if (tid < 256) q = fmask[node] ? NEGMIN : raw;
    int idx = n;
    #pragma unroll
    for (int off = 32; off >= 1; off >>= 1) {
        float ov = __shfl_down(q, off, 64);
        int oi  = __shfl_down(idx, off, 64);
        if (ov > q || (ov == q && oi < idx)) { q = ov; idx = oi; }
    }
    if (tid < 256 && (tid & 63) == 0) { redv[tid >> 6] = q; redi[tid >> 6] = idx; }
    __syncthreads();
    if (tid == 0) {
        float bv = redv[0]; int bi = redi[0];
        #pragma unroll
        for (int w = 1; w < 4; ++w) {
            float v = redv[w]; int iw = redi[w];
            if (v > bv || (v == bv && iw < bi)) { bv = v; bi = iw; }
        }
        out[g] = (float)bi;                 // indices (as float)
        out[512 + NTOT + g] = bv;           // values
    }
}

extern "C" void kernel_launch(void* const* d_in, const int* in_sizes, int n_in,
                              void* d_out, int out_size, void* d_ws, size_t ws_size,
                              hipStream_t stream)
{
    const float* nfg   = (const float*)d_in[0];
    const int*   esrc  = (const int*)d_in[1];
    const int*   fmask = (const int*)d_in[4];
    const float* Wn = (const float*)d_in[5];
    const float* bn = (const float*)d_in[6];
    const float* Wc = (const float*)d_in[7];
    const float* bc = (const float*)d_in[8];
    const float* W1 = (const float*)d_in[9];
    const float* b1 = (const float*)d_in[10];
    const float* W2 = (const float*)d_in[11];
    const float* b2 = (const float*)d_in[12];
    float* out = (float*)d_out;
    float* ws  = (float*)d_ws;

    prep_kernel<<<(WS_FLOATS + 255) / 256, 256, 0, stream>>>(Wn, bn, Wc, bc, W1, ws);

    size_t shmem = 18120 * sizeof(float);   // 72,480 B -> 2 blocks/CU (145 KB/160 KB)
    hipFuncSetAttribute((const void*)gdqn_kernel,
                        hipFuncAttributeMaxDynamicSharedMemorySize, (int)shmem);
    gdqn_kernel<<<NB, 512, shmem, stream>>>(nfg, esrc, fmask, ws, bn, b1, W2, b2, out);
}